// Round 5
// baseline (17580.052 us; speedup 1.0000x reference)
//
#include <hip/hip_runtime.h>
#include <math.h>

#define D 256
#define NH 4
#define HDIM 64
#define FFD 2048
#define NL 3
#define VOC 30000
#define BPTT 20
#define BATCH 64
#define NMAX (BPTT*BATCH)   /* 1280 */

// ---------------- img embed (+ mask in block 0) ----------------
__global__ __launch_bounds__(256) void k_img(const float* __restrict__ feats,
                                             const float* __restrict__ Wg,
                                             const float* __restrict__ bg,
                                             float* __restrict__ embeds,
                                             const int* __restrict__ ids,
                                             int* __restrict__ mask) {
  __shared__ float xs[2048];
  int b = blockIdx.x, tid = threadIdx.x;
  if (b == 0 && tid < 64) {
    int run = 1;
    for (int j = 0; j < BPTT; ++j) {
      if (j > 0 && ids[tid*BPTT + j] == 2) run = 0;
      mask[tid*BPTT + j] = run;
    }
  }
  for (int j = 0; j < 8; ++j) xs[tid + j*256] = feats[b*2048 + tid + j*256];
  __syncthreads();
  float acc = 0.f;
  for (int k = 0; k < 2048; k += 4) {
    float4 xv = *(const float4*)&xs[k];
    acc += xv.x * Wg[(k+0)*D + tid];
    acc += xv.y * Wg[(k+1)*D + tid];
    acc += xv.z * Wg[(k+2)*D + tid];
    acc += xv.w * Wg[(k+3)*D + tid];
  }
  embeds[b*D + tid] = acc + bg[tid];
}

// ---------------- GEMM tile: 8 tok x 256 cols, K=256 (qkv) ----------------
__global__ __launch_bounds__(256) void k_gemm(
    const float* __restrict__ A, int lda,
    const float* __restrict__ W,
    const float* __restrict__ bias,
    float* __restrict__ C, int M, int relu)
{
  __shared__ float As[2048];
  const int tid  = threadIdx.x;
  const int tok0 = blockIdx.x * 8;
  const int colb = blockIdx.y * 256;
  const int colg = tid & 63;
  const int tokg = tid >> 6;
  const int col  = colb + colg*4;
  int colL = col; if (colL > M-4) colL = M-4;

  float acc[2][4] = {{0.f,0.f,0.f,0.f},{0.f,0.f,0.f,0.f}};

#pragma unroll
  for (int j = 0; j < 8; ++j)
    As[j*256 + tid] = A[(long)(tok0 + j)*lda + tid];
  __syncthreads();
  const float* Wp = W + colL;
#pragma unroll 2
  for (int kk = 0; kk < 256; kk += 4) {
    float a0[4], a1[4], w[4][4];
    *(float4*)a0   = *(const float4*)&As[(tokg*2+0)*256 + kk];
    *(float4*)a1   = *(const float4*)&As[(tokg*2+1)*256 + kk];
    *(float4*)w[0] = *(const float4*)(Wp + (long)(kk+0)*M);
    *(float4*)w[1] = *(const float4*)(Wp + (long)(kk+1)*M);
    *(float4*)w[2] = *(const float4*)(Wp + (long)(kk+2)*M);
    *(float4*)w[3] = *(const float4*)(Wp + (long)(kk+3)*M);
#pragma unroll
    for (int c = 0; c < 4; ++c)
#pragma unroll
      for (int q = 0; q < 4; ++q) {
        acc[0][c] += a0[q] * w[q][c];
        acc[1][c] += a1[q] * w[q][c];
      }
  }

  if (col < M) {
    float bv[4] = {0.f,0.f,0.f,0.f};
    if (bias) *(float4*)bv = *(const float4*)(bias + col);
#pragma unroll
    for (int j = 0; j < 2; ++j) {
      float v[4];
#pragma unroll
      for (int c = 0; c < 4; ++c) {
        v[c] = acc[j][c] + bv[c];
        if (relu) v[c] = fmaxf(v[c], 0.f);
      }
      *(float4*)(C + (long)(tok0 + tokg*2 + j)*M + col) = *(float4*)v;
    }
  }
}

// ---------------- GEMM tile: 16 tok x 256 cols, K=256 (logits) ----------------
__global__ __launch_bounds__(256) void k_gemm16(
    const float* __restrict__ A,           // rows stride D
    const float* __restrict__ W,
    const float* __restrict__ bias,
    float* __restrict__ C, int M)
{
  __shared__ float As[16*260];
  const int tid  = threadIdx.x;
  const int tok0 = blockIdx.x * 16;
  const int colb = blockIdx.y * 256;
  const int colg = tid & 63;
  const int tokg = tid >> 6;
  const int col  = colb + colg*4;
  int colL = col; if (colL > M-4) colL = M-4;

#pragma unroll
  for (int t = 0; t < 4; ++t) {
    int i4 = tid + t*256;           // float4 index over 16x64
    int r = i4 >> 6, c4 = i4 & 63;
    *(float4*)&As[r*260 + c4*4] = *(const float4*)&A[(long)(tok0 + r)*D + c4*4];
  }
  __syncthreads();

  float acc[4][4] = {{0.f,0.f,0.f,0.f},{0.f,0.f,0.f,0.f},{0.f,0.f,0.f,0.f},{0.f,0.f,0.f,0.f}};
  const float* Wp = W + colL;
#pragma unroll 2
  for (int kk = 0; kk < 256; kk += 4) {
    float a[4][4], w[4][4];
    *(float4*)w[0] = *(const float4*)(Wp + (long)(kk+0)*M);
    *(float4*)w[1] = *(const float4*)(Wp + (long)(kk+1)*M);
    *(float4*)w[2] = *(const float4*)(Wp + (long)(kk+2)*M);
    *(float4*)w[3] = *(const float4*)(Wp + (long)(kk+3)*M);
    *(float4*)a[0] = *(const float4*)&As[(tokg*4+0)*260 + kk];
    *(float4*)a[1] = *(const float4*)&As[(tokg*4+1)*260 + kk];
    *(float4*)a[2] = *(const float4*)&As[(tokg*4+2)*260 + kk];
    *(float4*)a[3] = *(const float4*)&As[(tokg*4+3)*260 + kk];
#pragma unroll
    for (int j = 0; j < 4; ++j)
#pragma unroll
      for (int c = 0; c < 4; ++c)
#pragma unroll
        for (int q = 0; q < 4; ++q)
          acc[j][c] += a[j][q] * w[q][c];
  }

  if (col < M) {
    float bv[4] = {0.f,0.f,0.f,0.f};
    if (bias) *(float4*)bv = *(const float4*)(bias + col);
#pragma unroll
    for (int j = 0; j < 4; ++j) {
      float v[4];
#pragma unroll
      for (int c = 0; c < 4; ++c) v[c] = acc[j][c] + bv[c];
      *(float4*)(C + (long)(tok0 + tokg*4 + j)*M + col) = *(float4*)v;
    }
  }
}

// ---------------- attention for one (b,h): scores->softmax->PV (R1-verified) ----------------
__global__ __launch_bounds__(64) void k_attn(const float* __restrict__ qkv,
                                             float* __restrict__ o, int S)
{
  __shared__ float qs[BPTT*HDIM], ks[BPTT*HDIM], vs[BPTT*HDIM], ps[BPTT*(BPTT+1)];
  int bh = blockIdx.x;
  int b = bh & 63, h = bh >> 6;
  int d = threadIdx.x;
  for (int s = 0; s < S; ++s) {
    long base = (long)(s*BATCH + b)*(3*D) + h*HDIM + d;
    qs[s*HDIM+d] = qkv[base];
    ks[s*HDIM+d] = qkv[base + D];
    vs[s*HDIM+d] = qkv[base + 2*D];
  }
  __syncthreads();
  for (int p = d; p < S*S; p += 64) {
    int si = p / S, ti = p - si*S;
    float acc = 0.f;
#pragma unroll 4
    for (int k = 0; k < HDIM; ++k) acc += qs[si*HDIM+k] * ks[ti*HDIM+k];
    ps[si*(BPTT+1)+ti] = acc * 0.125f;
  }
  __syncthreads();
  if (d < S) {
    float m = -1e30f;
    for (int t = 0; t < S; ++t) m = fmaxf(m, ps[d*(BPTT+1)+t]);
    float sum = 0.f;
    for (int t = 0; t < S; ++t) { float e = expf(ps[d*(BPTT+1)+t] - m); ps[d*(BPTT+1)+t] = e; sum += e; }
    float inv = 1.0f / sum;
    for (int t = 0; t < S; ++t) ps[d*(BPTT+1)+t] *= inv;
  }
  __syncthreads();
  for (int s = 0; s < S; ++s) {
    float acc = 0.f;
    for (int t = 0; t < S; ++t) acc += ps[s*(BPTT+1)+t] * vs[t*HDIM+d];
    o[(long)(s*BATCH+b)*D + h*HDIM + d] = acc;
  }
}

// ---------------- fused: out = LN(X + o@Wo + bo), 8 tok (R4-verified) ----------------
__global__ __launch_bounds__(256) void k_projln(
    const float* __restrict__ Aop, const float* __restrict__ W,
    const float* __restrict__ X, const float* __restrict__ bias,
    const float* __restrict__ g, const float* __restrict__ be,
    float* __restrict__ out)
{
  __shared__ float As[2048];
  const int tid  = threadIdx.x;
  const int tok0 = blockIdx.x * 8;
  const int colg = tid & 63;
  const int tokg = tid >> 6;
  const int col  = colg*4;

  float acc[2][4] = {{0.f,0.f,0.f,0.f},{0.f,0.f,0.f,0.f}};

#pragma unroll
  for (int j = 0; j < 8; ++j)
    As[j*256 + tid] = Aop[(long)(tok0 + j)*D + tid];
  __syncthreads();
  const float* Wp = W + col;
#pragma unroll 2
  for (int kk = 0; kk < 256; kk += 4) {
    float a0[4], a1[4], w[4][4];
    *(float4*)a0   = *(const float4*)&As[(tokg*2+0)*256 + kk];
    *(float4*)a1   = *(const float4*)&As[(tokg*2+1)*256 + kk];
    *(float4*)w[0] = *(const float4*)(Wp + (long)(kk+0)*D);
    *(float4*)w[1] = *(const float4*)(Wp + (long)(kk+1)*D);
    *(float4*)w[2] = *(const float4*)(Wp + (long)(kk+2)*D);
    *(float4*)w[3] = *(const float4*)(Wp + (long)(kk+3)*D);
#pragma unroll
    for (int c = 0; c < 4; ++c)
#pragma unroll
      for (int q = 0; q < 4; ++q) {
        acc[0][c] += a0[q] * w[q][c];
        acc[1][c] += a1[q] * w[q][c];
      }
  }

  float bv[4], gv[4], bev[4];
  *(float4*)bv  = *(const float4*)(bias + col);
  *(float4*)gv  = *(const float4*)(g + col);
  *(float4*)bev = *(const float4*)(be + col);

#pragma unroll
  for (int j = 0; j < 2; ++j) {
    const int tok = tok0 + tokg*2 + j;
    float v[4];
    float4 xv = *(const float4*)(X + (long)tok*D + col);
    v[0] = acc[j][0] + bv[0] + xv.x;
    v[1] = acc[j][1] + bv[1] + xv.y;
    v[2] = acc[j][2] + bv[2] + xv.z;
    v[3] = acc[j][3] + bv[3] + xv.w;
    float s = v[0]+v[1]+v[2]+v[3];
#pragma unroll
    for (int off = 1; off < 64; off <<= 1) s += __shfl_xor(s, off);
    float mu = s * (1.0f/D);
    float q0=v[0]-mu, q1=v[1]-mu, q2=v[2]-mu, q3=v[3]-mu;
    float q = q0*q0+q1*q1+q2*q2+q3*q3;
#pragma unroll
    for (int off = 1; off < 64; off <<= 1) q += __shfl_xor(q, off);
    float inv = 1.0f / sqrtf(q * (1.0f/D) + 1e-5f);
    float ov[4];
    ov[0] = q0*inv*gv[0] + bev[0];
    ov[1] = q1*inv*gv[1] + bev[1];
    ov[2] = q2*inv*gv[2] + bev[2];
    ov[3] = q3*inv*gv[3] + bev[3];
    *(float4*)(out + (long)tok*D + col) = *(float4*)ov;
  }
}

// ---------------- fused FFN+LN: out = LN(x1 + relu(x1@W1+b1)@W2 + b2), 8 tok ----------------
__global__ __launch_bounds__(256) void k_ffln(
    const float* __restrict__ x1, const float* __restrict__ W1, const float* __restrict__ b1,
    const float* __restrict__ W2, const float* __restrict__ b2,
    const float* __restrict__ g, const float* __restrict__ be,
    float* __restrict__ out)
{
  __shared__ float xs[8*260];
  __shared__ float fc[8*260];
  const int tid  = threadIdx.x;
  const int tok0 = blockIdx.x * 8;
  const int colg = tid & 63;
  const int tokg = tid >> 6;
  const int col  = colg * 4;

#pragma unroll
  for (int j = 0; j < 8; ++j)
    xs[j*260 + tid] = x1[(long)(tok0 + j)*D + tid];
  __syncthreads();

  float acc2[2][4] = {{0.f,0.f,0.f,0.f},{0.f,0.f,0.f,0.f}};

  for (int c = 0; c < FFD/256; ++c) {
    // phase A: fc = relu(xs @ W1[:, c*256..+256) + b1)
    float fa[2][4] = {{0.f,0.f,0.f,0.f},{0.f,0.f,0.f,0.f}};
    const float* W1p = W1 + c*256 + col;
#pragma unroll 2
    for (int kk = 0; kk < 256; kk += 4) {
      float a0[4], a1[4], w[4][4];
      *(float4*)a0   = *(const float4*)&xs[(tokg*2+0)*260 + kk];
      *(float4*)a1   = *(const float4*)&xs[(tokg*2+1)*260 + kk];
      *(float4*)w[0] = *(const float4*)(W1p + (long)(kk+0)*FFD);
      *(float4*)w[1] = *(const float4*)(W1p + (long)(kk+1)*FFD);
      *(float4*)w[2] = *(const float4*)(W1p + (long)(kk+2)*FFD);
      *(float4*)w[3] = *(const float4*)(W1p + (long)(kk+3)*FFD);
#pragma unroll
      for (int c4 = 0; c4 < 4; ++c4)
#pragma unroll
        for (int q = 0; q < 4; ++q) {
          fa[0][c4] += a0[q] * w[q][c4];
          fa[1][c4] += a1[q] * w[q][c4];
        }
    }
    float bv1[4];
    *(float4*)bv1 = *(const float4*)(b1 + c*256 + col);
#pragma unroll
    for (int j = 0; j < 2; ++j) {
      float v[4];
#pragma unroll
      for (int c4 = 0; c4 < 4; ++c4) v[c4] = fmaxf(fa[j][c4] + bv1[c4], 0.f);
      *(float4*)&fc[(tokg*2+j)*260 + col] = *(float4*)v;
    }
    __syncthreads();
    // phase B: acc2 += fc @ W2[c*256..+256, :]
    const float* W2p = W2 + (long)(c*256)*D + col;
#pragma unroll 2
    for (int kk = 0; kk < 256; kk += 4) {
      float a0[4], a1[4], w[4][4];
      *(float4*)a0   = *(const float4*)&fc[(tokg*2+0)*260 + kk];
      *(float4*)a1   = *(const float4*)&fc[(tokg*2+1)*260 + kk];
      *(float4*)w[0] = *(const float4*)(W2p + (long)(kk+0)*D);
      *(float4*)w[1] = *(const float4*)(W2p + (long)(kk+1)*D);
      *(float4*)w[2] = *(const float4*)(W2p + (long)(kk+2)*D);
      *(float4*)w[3] = *(const float4*)(W2p + (long)(kk+3)*D);
#pragma unroll
      for (int c4 = 0; c4 < 4; ++c4)
#pragma unroll
        for (int q = 0; q < 4; ++q) {
          acc2[0][c4] += a0[q] * w[q][c4];
          acc2[1][c4] += a1[q] * w[q][c4];
        }
    }
    __syncthreads();   // safe to overwrite fc next chunk
  }

  // epilogue: LN(xs + acc2 + b2)
  float bv[4], gv[4], bev[4];
  *(float4*)bv  = *(const float4*)(b2 + col);
  *(float4*)gv  = *(const float4*)(g + col);
  *(float4*)bev = *(const float4*)(be + col);

#pragma unroll
  for (int j = 0; j < 2; ++j) {
    const int tok = tok0 + tokg*2 + j;
    float xv[4];
    *(float4*)xv = *(const float4*)&xs[(tokg*2+j)*260 + col];
    float v[4];
    v[0] = acc2[j][0] + bv[0] + xv[0];
    v[1] = acc2[j][1] + bv[1] + xv[1];
    v[2] = acc2[j][2] + bv[2] + xv[2];
    v[3] = acc2[j][3] + bv[3] + xv[3];
    float s = v[0]+v[1]+v[2]+v[3];
#pragma unroll
    for (int off = 1; off < 64; off <<= 1) s += __shfl_xor(s, off);
    float mu = s * (1.0f/D);
    float q0=v[0]-mu, q1=v[1]-mu, q2=v[2]-mu, q3=v[3]-mu;
    float q = q0*q0+q1*q1+q2*q2+q3*q3;
#pragma unroll
    for (int off = 1; off < 64; off <<= 1) q += __shfl_xor(q, off);
    float inv = 1.0f / sqrtf(q * (1.0f/D) + 1e-5f);
    float ov[4];
    ov[0] = q0*inv*gv[0] + bev[0];
    ov[1] = q1*inv*gv[1] + bev[1];
    ov[2] = q2*inv*gv[2] + bev[2];
    ov[3] = q3*inv*gv[3] + bev[3];
    *(float4*)(out + (long)tok*D + col) = *(float4*)ov;
  }
}

// ---------------- vocab softmax + argmax + outputs + next-embed ----------------
__global__ __launch_bounds__(256) void k_vocab(
    const float* __restrict__ logits, const int* __restrict__ mask,
    float* __restrict__ out_probs, float* __restrict__ out_words, float* __restrict__ out_eos,
    const float* __restrict__ emb, float* __restrict__ embeds, int step)
{
  __shared__ float redf[12];
  __shared__ int   redi[4];
  int b = blockIdx.x, tid = threadIdx.x;
  const float* lrow = logits + (long)b*VOC;

  float m = -1e30f;
  for (int c = tid; c < VOC; c += 256) m = fmaxf(m, lrow[c]);
  for (int off = 32; off; off >>= 1) m = fmaxf(m, __shfl_down(m, off));
  if ((tid & 63) == 0) redf[tid >> 6] = m;
  __syncthreads();
  float gmax = fmaxf(fmaxf(redf[0],redf[1]), fmaxf(redf[2],redf[3]));
  __syncthreads();

  float s = 0.f, em = -1.0f;
  int ei = VOC;
  for (int c = tid; c < VOC; c += 256) {
    float e = expf(lrow[c] - gmax);
    s += e;
    if (e > em) { em = e; ei = c; }
  }
  for (int off = 32; off; off >>= 1) {
    float em2 = __shfl_down(em, off);
    int   ei2 = __shfl_down(ei, off);
    if (em2 > em || (em2 == em && ei2 < ei)) { em = em2; ei = ei2; }
    s += __shfl_down(s, off);
  }
  if ((tid & 63) == 0) { redf[4+(tid>>6)] = s; redf[8+(tid>>6)] = em; redi[tid>>6] = ei; }
  __syncthreads();
  float Ssum = redf[4]+redf[5]+redf[6]+redf[7];
  em = redf[8]; ei = redi[0];
  for (int w = 1; w < 4; ++w)
    if (redf[8+w] > em || (redf[8+w] == em && redi[w] < ei)) { em = redf[8+w]; ei = redi[w]; }

  int mk = mask[b*BPTT + step];
  for (int c = tid; c < VOC; c += 256) {
    float p = expf(lrow[c] - gmax) / Ssum;
    float* op = out_probs + (long)b*VOC + c;
    if (step == 0) *op = p;
    else if (mk)   *op = fmaxf(*op, p);
    if (c == 2) out_eos[b*BPTT + step] = p;
  }
  if (tid == 0) out_words[b*BPTT + step] = mk ? (float)ei : 0.0f;
  if (step + 1 < BPTT)
    embeds[(long)((step+1)*BATCH + b)*D + tid] = emb[(long)ei*D + tid];
}

// ---------------- host ----------------
extern "C" void kernel_launch(void* const* d_in, const int* in_sizes, int n_in,
                              void* d_out, int out_size, void* d_ws, size_t ws_size,
                              hipStream_t stream) {
  const float* image_feats = (const float*)d_in[0];
  const int*   target      = (const int*)  d_in[1];
  const float* emb_table   = (const float*)d_in[2];
  const float* W_g2e       = (const float*)d_in[3];
  const float* b_g2e       = (const float*)d_in[4];
  const float* W_out       = (const float*)d_in[5];
  const float* b_out       = (const float*)d_in[6];
  const float* Wqkv        = (const float*)d_in[7];
  const float* bqkv        = (const float*)d_in[8];
  const float* Wo          = (const float*)d_in[9];
  const float* bo          = (const float*)d_in[10];
  const float* W1          = (const float*)d_in[11];
  const float* b1          = (const float*)d_in[12];
  const float* W2          = (const float*)d_in[13];
  const float* b2          = (const float*)d_in[14];
  const float* g1          = (const float*)d_in[15];
  const float* be1         = (const float*)d_in[16];
  const float* g2          = (const float*)d_in[17];
  const float* be2         = (const float*)d_in[18];

  float* out_probs = (float*)d_out;
  float* out_words = out_probs + (long)BATCH*VOC;
  float* out_eos   = out_words + BATCH*BPTT;

  char* ws = (char*)d_ws;
  float* embeds = (float*)ws;  ws += sizeof(float)*(long)NMAX*D;
  float* xbuf   = (float*)ws;  ws += sizeof(float)*(long)NMAX*D;
  float* qkvb   = (float*)ws;  ws += sizeof(float)*(long)NMAX*3*D;
  float* obuf   = (float*)ws;  ws += sizeof(float)*(long)NMAX*D;
  float* logits = (float*)ws;  ws += sizeof(float)*(long)BATCH*VOC;
  int*   maskb  = (int*)ws;    ws += sizeof(int)*BATCH*BPTT;

  k_img<<<BATCH, 256, 0, stream>>>(image_feats, W_g2e, b_g2e, embeds, target, maskb);

  for (int i = 0; i < BPTT; ++i) {
    const int S = i + 1, N = S * BATCH, ntt = N / 8;
    for (int l = 0; l < NL; ++l) {
      const float* X = (l == 0) ? embeds : xbuf;
      // qkv = X @ Wqkv + bqkv
      k_gemm<<<dim3(ntt, 3), 256, 0, stream>>>(X, D, Wqkv + (long)l*D*3*D, bqkv + (long)l*3*D,
                                               qkvb, 3*D, 0);
      // attention
      k_attn<<<dim3(BATCH*NH), 64, 0, stream>>>(qkvb, obuf, S);
      // x1 = LN(X + o@Wo + bo)
      k_projln<<<dim3(ntt), 256, 0, stream>>>(obuf, Wo + (long)l*D*D, X, bo + (long)l*D,
                                              g1 + (long)l*D, be1 + (long)l*D, xbuf);
      // x2 = LN(x1 + relu(x1@W1+b1)@W2 + b2)  (fully fused, in-place)
      k_ffln<<<dim3(ntt), 256, 0, stream>>>(xbuf, W1 + (long)l*D*FFD, b1 + (long)l*FFD,
                                            W2 + (long)l*FFD*D, b2 + (long)l*D,
                                            g2 + (long)l*D, be2 + (long)l*D, xbuf);
    }
    // logits for last-step token rows (16-tok tiles)
    k_gemm16<<<dim3(4, (VOC+255)/256), 256, 0, stream>>>(xbuf + (long)i*BATCH*D, W_out, b_out,
                                                         logits, VOC);
    // vocab softmax/argmax/outputs/next-embed
    k_vocab<<<dim3(BATCH), 256, 0, stream>>>(logits, maskb, out_probs, out_words, out_eos,
                                             emb_table, embeds, i);
  }
}

// Round 6
// 12718.482 us; speedup vs baseline: 1.3822x; 1.3822x over previous
//
#include <hip/hip_runtime.h>
#include <math.h>

#define D 256
#define NH 4
#define HDIM 64
#define FFD 2048
#define NL 3
#define VOC 30000
#define BPTT 20
#define BATCH 64
#define NMAX (BPTT*BATCH)   /* 1280 */

// ---------------- img embed (+ mask in block 0) ----------------
__global__ __launch_bounds__(256) void k_img(const float* __restrict__ feats,
                                             const float* __restrict__ Wg,
                                             const float* __restrict__ bg,
                                             float* __restrict__ embeds,
                                             const int* __restrict__ ids,
                                             int* __restrict__ mask) {
  __shared__ float xs[2048];
  int b = blockIdx.x, tid = threadIdx.x;
  if (b == 0 && tid < 64) {
    int run = 1;
    for (int j = 0; j < BPTT; ++j) {
      if (j > 0 && ids[tid*BPTT + j] == 2) run = 0;
      mask[tid*BPTT + j] = run;
    }
  }
  for (int j = 0; j < 8; ++j) xs[tid + j*256] = feats[b*2048 + tid + j*256];
  __syncthreads();
  float acc = 0.f;
  for (int k = 0; k < 2048; k += 4) {
    float4 xv = *(const float4*)&xs[k];
    acc += xv.x * Wg[(k+0)*D + tid];
    acc += xv.y * Wg[(k+1)*D + tid];
    acc += xv.z * Wg[(k+2)*D + tid];
    acc += xv.w * Wg[(k+3)*D + tid];
  }
  embeds[b*D + tid] = acc + bg[tid];
}

// ---------------- GEMM: 16 tok x 256 cols, K=256, 4x4/thread ----------------
// C[.,M] = A[.,lda] @ W[256,M] (+bias)(+relu). 2 FLOP per L1-byte (balanced).
__global__ __launch_bounds__(256) void k_gemm16(
    const float* __restrict__ A, int lda,
    const float* __restrict__ W,
    const float* __restrict__ bias,
    float* __restrict__ C, int M, int relu)
{
  __shared__ float As[16*260];
  const int tid  = threadIdx.x;
  const int tok0 = blockIdx.x * 16;
  const int colb = blockIdx.y * 256;
  const int colg = tid & 63;
  const int tokg = tid >> 6;
  const int col  = colb + colg*4;
  int colL = col; if (colL > M-4) colL = M-4;

#pragma unroll
  for (int t = 0; t < 4; ++t) {
    int i4 = tid + t*256;           // float4 index over 16 rows x 64 groups
    int r = i4 >> 6, c4 = i4 & 63;
    *(float4*)&As[r*260 + c4*4] = *(const float4*)&A[(long)(tok0 + r)*lda + c4*4];
  }
  __syncthreads();

  float acc[4][4] = {{0.f,0.f,0.f,0.f},{0.f,0.f,0.f,0.f},{0.f,0.f,0.f,0.f},{0.f,0.f,0.f,0.f}};
  const float* Wp = W + colL;
#pragma unroll 2
  for (int kk = 0; kk < 256; kk += 4) {
    float a[4][4], w[4][4];
    *(float4*)w[0] = *(const float4*)(Wp + (long)(kk+0)*M);
    *(float4*)w[1] = *(const float4*)(Wp + (long)(kk+1)*M);
    *(float4*)w[2] = *(const float4*)(Wp + (long)(kk+2)*M);
    *(float4*)w[3] = *(const float4*)(Wp + (long)(kk+3)*M);
    *(float4*)a[0] = *(const float4*)&As[(tokg*4+0)*260 + kk];
    *(float4*)a[1] = *(const float4*)&As[(tokg*4+1)*260 + kk];
    *(float4*)a[2] = *(const float4*)&As[(tokg*4+2)*260 + kk];
    *(float4*)a[3] = *(const float4*)&As[(tokg*4+3)*260 + kk];
#pragma unroll
    for (int j = 0; j < 4; ++j)
#pragma unroll
      for (int c = 0; c < 4; ++c)
#pragma unroll
        for (int q = 0; q < 4; ++q)
          acc[j][c] += a[j][q] * w[q][c];
  }

  if (col < M) {
    float bv[4] = {0.f,0.f,0.f,0.f};
    if (bias) *(float4*)bv = *(const float4*)(bias + col);
#pragma unroll
    for (int j = 0; j < 4; ++j) {
      float v[4];
#pragma unroll
      for (int c = 0; c < 4; ++c) {
        v[c] = acc[j][c] + bv[c];
        if (relu) v[c] = fmaxf(v[c], 0.f);
      }
      *(float4*)(C + (long)(tok0 + tokg*4 + j)*M + col) = *(float4*)v;
    }
  }
}

// ---------------- attention for one (b,h), qs/ks padded (stride 68) ----------------
__global__ __launch_bounds__(64) void k_attn(const float* __restrict__ qkv,
                                             float* __restrict__ o, int S)
{
  __shared__ float qs[BPTT*68], ks[BPTT*68], vs[BPTT*HDIM], ps[BPTT*(BPTT+1)];
  int bh = blockIdx.x;
  int b = bh & 63, h = bh >> 6;
  int d = threadIdx.x;
  for (int s = 0; s < S; ++s) {
    long base = (long)(s*BATCH + b)*(3*D) + h*HDIM + d;
    qs[s*68+d]   = qkv[base];
    ks[s*68+d]   = qkv[base + D];
    vs[s*HDIM+d] = qkv[base + 2*D];
  }
  __syncthreads();
  for (int p = d; p < S*S; p += 64) {
    int si = p / S, ti = p - si*S;
    float acc = 0.f;
#pragma unroll 4
    for (int k = 0; k < HDIM; ++k) acc += qs[si*68+k] * ks[ti*68+k];
    ps[si*(BPTT+1)+ti] = acc * 0.125f;
  }
  __syncthreads();
  if (d < S) {
    float m = -1e30f;
    for (int t = 0; t < S; ++t) m = fmaxf(m, ps[d*(BPTT+1)+t]);
    float sum = 0.f;
    for (int t = 0; t < S; ++t) { float e = expf(ps[d*(BPTT+1)+t] - m); ps[d*(BPTT+1)+t] = e; sum += e; }
    float inv = 1.0f / sum;
    for (int t = 0; t < S; ++t) ps[d*(BPTT+1)+t] *= inv;
  }
  __syncthreads();
  for (int s = 0; s < S; ++s) {
    float acc = 0.f;
    for (int t = 0; t < S; ++t) acc += ps[s*(BPTT+1)+t] * vs[t*HDIM+d];
    o[(long)(s*BATCH+b)*D + h*HDIM + d] = acc;
  }
}

// ---------------- fused: out = LN(X + o@Wo + bo), 8 tok ----------------
__global__ __launch_bounds__(256) void k_projln(
    const float* __restrict__ Aop, const float* __restrict__ W,
    const float* __restrict__ X, const float* __restrict__ bias,
    const float* __restrict__ g, const float* __restrict__ be,
    float* __restrict__ out)
{
  __shared__ float As[2048];
  const int tid  = threadIdx.x;
  const int tok0 = blockIdx.x * 8;
  const int colg = tid & 63;
  const int tokg = tid >> 6;
  const int col  = colg*4;

  float acc[2][4] = {{0.f,0.f,0.f,0.f},{0.f,0.f,0.f,0.f}};

#pragma unroll
  for (int j = 0; j < 8; ++j)
    As[j*256 + tid] = Aop[(long)(tok0 + j)*D + tid];
  __syncthreads();
  const float* Wp = W + col;
#pragma unroll 2
  for (int kk = 0; kk < 256; kk += 4) {
    float a0[4], a1[4], w[4][4];
    *(float4*)a0   = *(const float4*)&As[(tokg*2+0)*256 + kk];
    *(float4*)a1   = *(const float4*)&As[(tokg*2+1)*256 + kk];
    *(float4*)w[0] = *(const float4*)(Wp + (long)(kk+0)*D);
    *(float4*)w[1] = *(const float4*)(Wp + (long)(kk+1)*D);
    *(float4*)w[2] = *(const float4*)(Wp + (long)(kk+2)*D);
    *(float4*)w[3] = *(const float4*)(Wp + (long)(kk+3)*D);
#pragma unroll
    for (int c = 0; c < 4; ++c)
#pragma unroll
      for (int q = 0; q < 4; ++q) {
        acc[0][c] += a0[q] * w[q][c];
        acc[1][c] += a1[q] * w[q][c];
      }
  }

  float bv[4], gv[4], bev[4];
  *(float4*)bv  = *(const float4*)(bias + col);
  *(float4*)gv  = *(const float4*)(g + col);
  *(float4*)bev = *(const float4*)(be + col);

#pragma unroll
  for (int j = 0; j < 2; ++j) {
    const int tok = tok0 + tokg*2 + j;
    float v[4];
    float4 xv = *(const float4*)(X + (long)tok*D + col);
    v[0] = acc[j][0] + bv[0] + xv.x;
    v[1] = acc[j][1] + bv[1] + xv.y;
    v[2] = acc[j][2] + bv[2] + xv.z;
    v[3] = acc[j][3] + bv[3] + xv.w;
    float s = v[0]+v[1]+v[2]+v[3];
#pragma unroll
    for (int off = 1; off < 64; off <<= 1) s += __shfl_xor(s, off);
    float mu = s * (1.0f/D);
    float q0=v[0]-mu, q1=v[1]-mu, q2=v[2]-mu, q3=v[3]-mu;
    float q = q0*q0+q1*q1+q2*q2+q3*q3;
#pragma unroll
    for (int off = 1; off < 64; off <<= 1) q += __shfl_xor(q, off);
    float inv = 1.0f / sqrtf(q * (1.0f/D) + 1e-5f);
    float ov[4];
    ov[0] = q0*inv*gv[0] + bev[0];
    ov[1] = q1*inv*gv[1] + bev[1];
    ov[2] = q2*inv*gv[2] + bev[2];
    ov[3] = q3*inv*gv[3] + bev[3];
    *(float4*)(out + (long)tok*D + col) = *(float4*)ov;
  }
}

// ---------------- fused FF2+res+LN: out = LN(x1 + ff@W2 + b2), 8 tok ----------------
// 4 waves own disjoint K-quarters (W2 crosses L1 exactly once per block);
// A (ff rows) read as wave-uniform global float4; LDS only for reduce+LN.
__global__ __launch_bounds__(256) void k_ff2ln(
    const float* __restrict__ ff, const float* __restrict__ W2,
    const float* __restrict__ x1, const float* __restrict__ b2,
    const float* __restrict__ g, const float* __restrict__ be,
    float* __restrict__ out)
{
  __shared__ float part[4][8][260];
  const int tid  = threadIdx.x;
  const int tok0 = blockIdx.x * 8;
  const int w    = tid >> 6;       // K-quarter
  const int lane = tid & 63;
  const int col  = lane * 4;
  const int kbeg = w * 512;

  float acc[8][4];
#pragma unroll
  for (int t = 0; t < 8; ++t)
#pragma unroll
    for (int c = 0; c < 4; ++c) acc[t][c] = 0.f;

  const float* Wp  = W2 + (long)kbeg*D + col;
  const float* ffp = ff + (long)tok0*FFD + kbeg;
#pragma unroll 1
  for (int kk = 0; kk < 512; kk += 4) {
    float a[8][4], w4[4][4];
#pragma unroll
    for (int t = 0; t < 8; ++t)
      *(float4*)a[t] = *(const float4*)(ffp + (long)t*FFD + kk);
    *(float4*)w4[0] = *(const float4*)(Wp + (long)(kk+0)*D);
    *(float4*)w4[1] = *(const float4*)(Wp + (long)(kk+1)*D);
    *(float4*)w4[2] = *(const float4*)(Wp + (long)(kk+2)*D);
    *(float4*)w4[3] = *(const float4*)(Wp + (long)(kk+3)*D);
#pragma unroll
    for (int t = 0; t < 8; ++t)
#pragma unroll
      for (int c = 0; c < 4; ++c)
#pragma unroll
        for (int q = 0; q < 4; ++q)
          acc[t][c] += a[t][q] * w4[q][c];
  }

#pragma unroll
  for (int t = 0; t < 8; ++t)
    *(float4*)&part[w][t][col] = *(float4*)acc[t];
  __syncthreads();

  // wave w handles tokens 2w, 2w+1
  float bv[4], gv[4], bev[4];
  *(float4*)bv  = *(const float4*)(b2 + col);
  *(float4*)gv  = *(const float4*)(g + col);
  *(float4*)bev = *(const float4*)(be + col);

#pragma unroll
  for (int j = 0; j < 2; ++j) {
    const int t = w*2 + j;
    const int tok = tok0 + t;
    float v[4], p0[4], p1[4], p2[4], p3[4], xv[4];
    *(float4*)p0 = *(float4*)&part[0][t][col];
    *(float4*)p1 = *(float4*)&part[1][t][col];
    *(float4*)p2 = *(float4*)&part[2][t][col];
    *(float4*)p3 = *(float4*)&part[3][t][col];
    *(float4*)xv = *(const float4*)(x1 + (long)tok*D + col);
#pragma unroll
    for (int c = 0; c < 4; ++c) v[c] = p0[c]+p1[c]+p2[c]+p3[c] + bv[c] + xv[c];
    float s = v[0]+v[1]+v[2]+v[3];
#pragma unroll
    for (int off = 1; off < 64; off <<= 1) s += __shfl_xor(s, off);
    float mu = s * (1.0f/D);
    float q0=v[0]-mu, q1=v[1]-mu, q2=v[2]-mu, q3=v[3]-mu;
    float q = q0*q0+q1*q1+q2*q2+q3*q3;
#pragma unroll
    for (int off = 1; off < 64; off <<= 1) q += __shfl_xor(q, off);
    float inv = 1.0f / sqrtf(q * (1.0f/D) + 1e-5f);
    float ov[4];
    ov[0] = q0*inv*gv[0] + bev[0];
    ov[1] = q1*inv*gv[1] + bev[1];
    ov[2] = q2*inv*gv[2] + bev[2];
    ov[3] = q3*inv*gv[3] + bev[3];
    *(float4*)(out + (long)tok*D + col) = *(float4*)ov;
  }
}

// ---------------- vocab softmax + argmax + outputs + next-embed ----------------
__global__ __launch_bounds__(256) void k_vocab(
    const float* __restrict__ logits, const int* __restrict__ mask,
    float* __restrict__ out_probs, float* __restrict__ out_words, float* __restrict__ out_eos,
    const float* __restrict__ emb, float* __restrict__ embeds, int step)
{
  __shared__ float redf[12];
  __shared__ int   redi[4];
  int b = blockIdx.x, tid = threadIdx.x;
  const float* lrow = logits + (long)b*VOC;

  float m = -1e30f;
  for (int c = tid; c < VOC; c += 256) m = fmaxf(m, lrow[c]);
  for (int off = 32; off; off >>= 1) m = fmaxf(m, __shfl_down(m, off));
  if ((tid & 63) == 0) redf[tid >> 6] = m;
  __syncthreads();
  float gmax = fmaxf(fmaxf(redf[0],redf[1]), fmaxf(redf[2],redf[3]));
  __syncthreads();

  float s = 0.f, em = -1.0f;
  int ei = VOC;
  for (int c = tid; c < VOC; c += 256) {
    float e = expf(lrow[c] - gmax);
    s += e;
    if (e > em) { em = e; ei = c; }
  }
  for (int off = 32; off; off >>= 1) {
    float em2 = __shfl_down(em, off);
    int   ei2 = __shfl_down(ei, off);
    if (em2 > em || (em2 == em && ei2 < ei)) { em = em2; ei = ei2; }
    s += __shfl_down(s, off);
  }
  if ((tid & 63) == 0) { redf[4+(tid>>6)] = s; redf[8+(tid>>6)] = em; redi[tid>>6] = ei; }
  __syncthreads();
  float Ssum = redf[4]+redf[5]+redf[6]+redf[7];
  em = redf[8]; ei = redi[0];
  for (int w = 1; w < 4; ++w)
    if (redf[8+w] > em || (redf[8+w] == em && redi[w] < ei)) { em = redf[8+w]; ei = redi[w]; }

  int mk = mask[b*BPTT + step];
  for (int c = tid; c < VOC; c += 256) {
    float p = expf(lrow[c] - gmax) / Ssum;
    float* op = out_probs + (long)b*VOC + c;
    if (step == 0) *op = p;
    else if (mk)   *op = fmaxf(*op, p);
    if (c == 2) out_eos[b*BPTT + step] = p;
  }
  if (tid == 0) out_words[b*BPTT + step] = mk ? (float)ei : 0.0f;
  if (step + 1 < BPTT)
    embeds[(long)((step+1)*BATCH + b)*D + tid] = emb[(long)ei*D + tid];
}

// ---------------- host ----------------
extern "C" void kernel_launch(void* const* d_in, const int* in_sizes, int n_in,
                              void* d_out, int out_size, void* d_ws, size_t ws_size,
                              hipStream_t stream) {
  const float* image_feats = (const float*)d_in[0];
  const int*   target      = (const int*)  d_in[1];
  const float* emb_table   = (const float*)d_in[2];
  const float* W_g2e       = (const float*)d_in[3];
  const float* b_g2e       = (const float*)d_in[4];
  const float* W_out       = (const float*)d_in[5];
  const float* b_out       = (const float*)d_in[6];
  const float* Wqkv        = (const float*)d_in[7];
  const float* bqkv        = (const float*)d_in[8];
  const float* Wo          = (const float*)d_in[9];
  const float* bo          = (const float*)d_in[10];
  const float* W1          = (const float*)d_in[11];
  const float* b1          = (const float*)d_in[12];
  const float* W2          = (const float*)d_in[13];
  const float* b2          = (const float*)d_in[14];
  const float* g1          = (const float*)d_in[15];
  const float* be1         = (const float*)d_in[16];
  const float* g2          = (const float*)d_in[17];
  const float* be2         = (const float*)d_in[18];

  float* out_probs = (float*)d_out;
  float* out_words = out_probs + (long)BATCH*VOC;
  float* out_eos   = out_words + BATCH*BPTT;

  char* ws = (char*)d_ws;
  float* embeds = (float*)ws;  ws += sizeof(float)*(long)NMAX*D;
  float* xbuf   = (float*)ws;  ws += sizeof(float)*(long)NMAX*D;
  float* qkvb   = (float*)ws;  ws += sizeof(float)*(long)NMAX*3*D;
  float* obuf   = (float*)ws;  ws += sizeof(float)*(long)NMAX*D;
  float* ffb    = (float*)ws;  ws += sizeof(float)*(long)NMAX*FFD;
  float* logits = (float*)ws;  ws += sizeof(float)*(long)BATCH*VOC;
  int*   maskb  = (int*)ws;    ws += sizeof(int)*BATCH*BPTT;

  k_img<<<BATCH, 256, 0, stream>>>(image_feats, W_g2e, b_g2e, embeds, target, maskb);

  for (int i = 0; i < BPTT; ++i) {
    const int S = i + 1, N = S * BATCH;
    const int nt16 = N / 16, nt8 = N / 8;
    for (int l = 0; l < NL; ++l) {
      const float* X = (l == 0) ? embeds : xbuf;
      // qkv = X @ Wqkv + bqkv
      k_gemm16<<<dim3(nt16, 3), 256, 0, stream>>>(X, D, Wqkv + (long)l*D*3*D, bqkv + (long)l*3*D,
                                                  qkvb, 3*D, 0);
      // attention
      k_attn<<<dim3(BATCH*NH), 64, 0, stream>>>(qkvb, obuf, S);
      // x1 = LN(X + o@Wo + bo)
      k_projln<<<dim3(nt8), 256, 0, stream>>>(obuf, Wo + (long)l*D*D, X, bo + (long)l*D,
                                              g1 + (long)l*D, be1 + (long)l*D, xbuf);
      // ff = relu(x1 @ W1 + b1)
      k_gemm16<<<dim3(nt16, FFD/256), 256, 0, stream>>>(xbuf, D, W1 + (long)l*D*FFD, b1 + (long)l*FFD,
                                                        ffb, FFD, 1);
      // x2 = LN(x1 + ff@W2 + b2)  (fused, in-place per-block rows)
      k_ff2ln<<<dim3(nt8), 256, 0, stream>>>(ffb, W2 + (long)l*FFD*D, xbuf, b2 + (long)l*D,
                                             g2 + (long)l*D, be2 + (long)l*D, xbuf);
    }
    // logits for last-step token rows
    k_gemm16<<<dim3(4, (VOC+255)/256), 256, 0, stream>>>(xbuf + (long)i*BATCH*D, D, W_out, b_out,
                                                         logits, VOC, 0);
    // vocab softmax/argmax/outputs/next-embed
    k_vocab<<<dim3(BATCH), 256, 0, stream>>>(logits, maskb, out_probs, out_words, out_eos,
                                             emb_table, embeds, i);
  }
}